// Round 1
// baseline (1474.908 us; speedup 1.0000x reference)
//
#include <hip/hip_runtime.h>
#include <hip/hip_bf16.h>

#define Bb 4
#define Hh 8
#define Ll 8192
#define Dd 64
#define Cc 256
#define Ww 32
#define TL 64   // tokens per k1 block

// ---------------- k1: dists GEMM + argmax buckets + loss partials + dist_T write ----------------
// grid (Ll/TL, hStep), block 256. thread tile: 4 tokens x 16 clusters (both stride-16 interleaved).
__global__ __launch_bounds__(256) void k1_gemm(const float* __restrict__ x,
                                               const float* __restrict__ means,
                                               float* __restrict__ distT,
                                               int* __restrict__ buckets,
                                               float* __restrict__ lossP,
                                               int b, int h0) {
    __shared__ __align__(16) float ms[128 * 68];   // half of means[h], padded rows
    __shared__ __align__(16) float xs[TL * 68];    // token tile, padded rows
    __shared__ float pv[TL * 16];
    __shared__ int   pc[TL * 16];
    __shared__ float msq[256];
    __shared__ float lossAcc;

    const int tid = threadIdx.x;
    const int hl  = blockIdx.y;
    const int h   = h0 + hl;
    const int l0  = blockIdx.x * TL;
    const int tg  = tid & 15;    // token group: tokens t = tg + 16*jt
    const int cg  = tid >> 4;    // cluster group: clusters c = cg + 128*p + 16*jl

    if (tid == 0) lossAcc = 0.f;

    // stage x tile: xs[t*68 + k]
    const float* xbase = x + (((size_t)(b * Hh + h)) * Ll + l0) * Dd;
    for (int j = tid; j < TL * Dd / 4; j += 256) {
        int t = j >> 4, k4 = (j & 15) << 2;
        float4 v = *(const float4*)(xbase + t * Dd + k4);
        xs[t * 68 + k4 + 0] = v.x; xs[t * 68 + k4 + 1] = v.y;
        xs[t * 68 + k4 + 2] = v.z; xs[t * 68 + k4 + 3] = v.w;
    }

    float acc[4][16];
    #pragma unroll
    for (int jt = 0; jt < 4; jt++)
        #pragma unroll
        for (int jc = 0; jc < 16; jc++) acc[jt][jc] = 0.f;

    for (int p = 0; p < 2; p++) {
        __syncthreads();  // covers xs staging (p=0) / protects ms from prev-pass readers (p=1)
        const float* mbase = means + ((size_t)h * Cc + p * 128) * Dd;
        for (int j = tid; j < 128 * Dd / 4; j += 256) {
            int cr = j >> 4, k4 = (j & 15) << 2;
            float4 v = *(const float4*)(mbase + cr * Dd + k4);
            ms[cr * 68 + k4 + 0] = v.x; ms[cr * 68 + k4 + 1] = v.y;
            ms[cr * 68 + k4 + 2] = v.z; ms[cr * 68 + k4 + 3] = v.w;
        }
        __syncthreads();
        if (tid < 128) {  // |m_c|^2 for the loss
            float s = 0.f;
            #pragma unroll 8
            for (int k = 0; k < 64; k += 2) {
                float2 m = *(float2*)&ms[tid * 68 + k];
                s = fmaf(m.x, m.x, s); s = fmaf(m.y, m.y, s);
            }
            msq[p * 128 + tid] = s;
        }
        #pragma unroll 4
        for (int k = 0; k < 64; k += 2) {
            float2 xa[4];
            #pragma unroll
            for (int jt = 0; jt < 4; jt++) xa[jt] = *(float2*)&xs[(tg + 16 * jt) * 68 + k];
            float2 mb[8];
            #pragma unroll
            for (int jl = 0; jl < 8; jl++) mb[jl] = *(float2*)&ms[(cg + 16 * jl) * 68 + k];
            #pragma unroll
            for (int jt = 0; jt < 4; jt++)
                #pragma unroll
                for (int jl = 0; jl < 8; jl++) {
                    float a = acc[jt][p * 8 + jl];
                    a = fmaf(xa[jt].x, mb[jl].x, a);
                    a = fmaf(xa[jt].y, mb[jl].y, a);
                    acc[jt][p * 8 + jl] = a;
                }
        }
    }

    // dist_T writes + per-thread argmax partial (ascending c within thread -> keep-first tie rule)
    #pragma unroll
    for (int jt = 0; jt < 4; jt++) {
        int t = tg + 16 * jt;
        float bv = acc[jt][0]; int bc = cg;  // jc=0 -> c=cg
        #pragma unroll
        for (int jc = 0; jc < 16; jc++) {
            int c = cg + 128 * (jc >> 3) + 16 * (jc & 7);
            float v = acc[jt][jc];
            distT[((size_t)(hl * Cc + c)) * Ll + l0 + t] = v;
            if (jc > 0 && v > bv) { bv = v; bc = c; }
        }
        pv[t * 16 + cg] = bv; pc[t * 16 + cg] = bc;
    }
    __syncthreads();

    if (tid < TL) {
        int t = tid;
        float ss = 0.f;
        #pragma unroll 8
        for (int k = 0; k < 64; k += 2) {
            float2 v = *(float2*)&xs[t * 68 + k];
            ss = fmaf(v.x, v.x, ss); ss = fmaf(v.y, v.y, ss);
        }
        float bv = pv[t * 16]; int bc = pc[t * 16];
        #pragma unroll
        for (int g = 1; g < 16; g++) {
            float v = pv[t * 16 + g]; int c2 = pc[t * 16 + g];
            if (v > bv || (v == bv && c2 < bc)) { bv = v; bc = c2; }
        }
        buckets[((size_t)(b * Hh + h)) * Ll + l0 + t] = bc;
        atomicAdd(&lossAcc, ss - 2.f * bv + msq[bc]);
    }
    __syncthreads();
    if (tid == 0) lossP[(b * Hh + h) * (Ll / TL) + blockIdx.x] = lossAcc;
}

// ---------------- k2: exact top-32 per (h,c) column via 4-pass radix select ----------------
__device__ __forceinline__ unsigned int f2key(float f) {
    unsigned int u = __float_as_uint(f);
    return (u & 0x80000000u) ? ~u : (u | 0x80000000u);
}

__global__ __launch_bounds__(256) void k2_topk(const float* __restrict__ distT,
                                               float* __restrict__ outIdx,
                                               int b, int h0) {
    __shared__ unsigned int hist[256];
    __shared__ unsigned int gsum[16];
    __shared__ unsigned int sA, sPrefix, sNA, sEq;
    __shared__ int aboveList[32];
    __shared__ int eqList[64];
    __shared__ int comb[32];

    const int tid = threadIdx.x;
    const int c = blockIdx.x;
    const int hl = blockIdx.y;
    const int h = h0 + hl;
    const float* col = distT + ((size_t)(hl * Cc + c)) * Ll;

    unsigned int key[32];
    #pragma unroll
    for (int j = 0; j < 8; j++) {
        float4 v = *(const float4*)(col + j * 1024 + tid * 4);
        key[j * 4 + 0] = f2key(v.x); key[j * 4 + 1] = f2key(v.y);
        key[j * 4 + 2] = f2key(v.z); key[j * 4 + 3] = f2key(v.w);
    }
    if (tid == 0) { sA = 0; sPrefix = 0; }
    __syncthreads();

    for (int pass = 0; pass < 4; pass++) {
        const int shift = 24 - 8 * pass;
        unsigned int A = sA, pref = sPrefix;
        unsigned int maskHi = (pass == 0) ? 0u : (0xFFFFFFFFu << (shift + 8));
        hist[tid] = 0;
        __syncthreads();
        #pragma unroll
        for (int j = 0; j < 32; j++)
            if (((key[j] ^ pref) & maskHi) == 0)
                atomicAdd(&hist[(key[j] >> shift) & 255], 1u);
        __syncthreads();
        if (tid < 16) {
            unsigned int s = 0;
            for (int j = 0; j < 16; j++) s += hist[tid * 16 + j];
            gsum[tid] = s;
        }
        __syncthreads();
        // suffixIncl(tid)
        unsigned int suf = 0;
        int g = tid >> 4;
        for (int j = tid; j < (g + 1) * 16; j++) suf += hist[j];
        for (int j = g + 1; j < 16; j++) suf += gsum[j];
        unsigned int sufNext = suf - hist[tid];
        bool cond = (A + suf) >= Ww;
        bool condNext = (A + sufNext) >= Ww;
        if (cond && (tid == 255 || !condNext)) {
            sA = A + sufNext;
            sPrefix = pref | ((unsigned int)tid << shift);
        }
        __syncthreads();
    }

    const unsigned int T = sPrefix;
    const int nAexp = (int)sA;
    const int r = Ww - nAexp;
    if (tid == 0) { sNA = 0; sEq = 0; }
    __syncthreads();
    #pragma unroll
    for (int j = 0; j < 32; j++) {
        unsigned int kk = key[j];
        int idx = 4 * (j / 4) * 256 + tid * 4 + (j & 3);  // = (j>>2)*1024 + tid*4 + (j&3)
        if (kk > T) {
            int p2 = (int)atomicAdd(&sNA, 1u);
            if (p2 < 32) aboveList[p2] = idx;
        } else if (kk == T) {
            int p2 = (int)atomicAdd(&sEq, 1u);
            if (p2 < 64) eqList[p2] = idx;
        }
    }
    __syncthreads();
    const int nA = (int)sNA;
    const int eq = (int)sEq;
    if (eq <= 64) {
        if (tid < eq) {
            int v = eqList[tid];
            int rank = 0;
            for (int j = 0; j < eq; j++) rank += (eqList[j] < v);
            if (rank < r) comb[nA + rank] = v;
        }
    } else if (tid == 0) {  // pathological tie flood: serial, correct
        int taken = 0;
        for (int i = 0; i < Ll && taken < r; i++)
            if (f2key(col[i]) == T) comb[nA + taken++] = i;
    }
    if (tid < nA) comb[tid] = aboveList[tid];
    __syncthreads();
    if (tid < Ww) {
        int v = comb[tid];
        int rank = 0;
        #pragma unroll
        for (int j = 0; j < Ww; j++) rank += (comb[j] < v);
        outIdx[(((size_t)b * Hh + h) * Cc + c) * Ww + rank] = (float)v;
    }
}

// ---------------- k3: scatter-mean + normalize -> new_means ----------------
__global__ __launch_bounds__(256) void k3_means(const float* __restrict__ x,
                                                const float* __restrict__ means,
                                                const int* __restrict__ buckets,
                                                float* __restrict__ outMeans) {
    __shared__ float sums[64];
    __shared__ int cnt;
    __shared__ float snorm;
    const int tid = threadIdx.x;
    const int c = blockIdx.x, h = blockIdx.y;
    if (tid < 64) sums[tid] = 0.f;
    if (tid == 0) cnt = 0;
    __syncthreads();
    for (int i = tid; i < Bb * Ll; i += 256) {
        int bb = i >> 13;
        int l = i & (Ll - 1);
        int bk = buckets[((size_t)(bb * Hh + h)) * Ll + l];
        if (bk == c) {
            atomicAdd(&cnt, 1);
            const float* xr = x + (((size_t)(bb * Hh + h)) * Ll + l) * Dd;
            for (int d2 = 0; d2 < 64; d2++) atomicAdd(&sums[d2], xr[d2]);
        }
    }
    __syncthreads();
    if (tid == 0) {
        float s = 0.f;
        for (int d2 = 0; d2 < 64; d2++) s += sums[d2] * sums[d2];
        snorm = sqrtf(s);
    }
    __syncthreads();
    if (tid < 64) {
        float outv;
        if (cnt == 0) outv = means[((size_t)(h * Cc + c)) * 64 + tid];
        else outv = sums[tid] / fmaxf(snorm, 1e-12f);
        outMeans[((size_t)(h * Cc + c)) * 64 + tid] = outv;
    }
}

// ---------------- k4: loss reduction ----------------
__global__ __launch_bounds__(256) void k4_loss(const float* __restrict__ lossP,
                                               float* __restrict__ out) {
    __shared__ float red[256];
    const int tid = threadIdx.x;
    float s = 0.f;
    for (int i = tid; i < Bb * Hh * (Ll / TL); i += 256) s += lossP[i];
    red[tid] = s;
    __syncthreads();
    for (int off = 128; off; off >>= 1) {
        if (tid < off) red[tid] += red[tid + off];
        __syncthreads();
    }
    if (tid == 0)
        out[(size_t)Bb * Hh * Cc * Ww] = red[0] * (1e-4f / (float)((size_t)Bb * Hh * Ll * Dd));
}

extern "C" void kernel_launch(void* const* d_in, const int* in_sizes, int n_in,
                              void* d_out, int out_size, void* d_ws, size_t ws_size,
                              hipStream_t stream) {
    const float* x = (const float*)d_in[0];
    const float* means = (const float*)d_in[1];
    float* out = (float*)d_out;

    char* ws = (char*)d_ws;
    float* lossP = (float*)ws;                                  // 4096 floats
    int* buckets = (int*)(ws + 16384);                          // 262144 ints = 1 MB
    float* distT = (float*)(ws + 16384 + 1048576);              // hStep * 8 MB
    const size_t fixed = 16384 + 1048576;
    const size_t perH = (size_t)Cc * Ll * 4;

    int hStep = 8;
    while (hStep > 1 && fixed + (size_t)hStep * perH > ws_size) hStep >>= 1;

    const int IDXN = Bb * Hh * Cc * Ww;  // 262144
    for (int b = 0; b < Bb; b++) {
        for (int h0 = 0; h0 < Hh; h0 += hStep) {
            k1_gemm<<<dim3(Ll / TL, hStep), 256, 0, stream>>>(x, means, distT, buckets, lossP, b, h0);
            k2_topk<<<dim3(Cc, hStep), 256, 0, stream>>>(distT, out, b, h0);
        }
    }
    k3_means<<<dim3(Cc, Hh), 256, 0, stream>>>(x, means, buckets, out + IDXN + 1);
    k4_loss<<<1, 256, 0, stream>>>(lossP, out);
}

// Round 2
// 583.612 us; speedup vs baseline: 2.5272x; 2.5272x over previous
//
#include <hip/hip_runtime.h>
#include <hip/hip_bf16.h>

#define Bb 4
#define Hh 8
#define Ll 8192
#define Dd 64
#define Cc 256
#define Ww 32
#define TL 64   // tokens per k1 block

// ---------------- k1: dists GEMM + argmax buckets + loss partials + dist_T write ----------------
// grid (Ll/TL, hStep), block 256. thread tile: 4 tokens x 16 clusters (both stride-16 interleaved).
__global__ __launch_bounds__(256) void k1_gemm(const float* __restrict__ x,
                                               const float* __restrict__ means,
                                               float* __restrict__ distT,
                                               int* __restrict__ buckets,
                                               float* __restrict__ lossP,
                                               int b, int h0) {
    __shared__ __align__(16) float ms[128 * 68];   // half of means[h], padded rows
    __shared__ __align__(16) float xs[TL * 68];    // token tile, padded rows
    __shared__ float pv[TL * 16];
    __shared__ int   pc[TL * 16];
    __shared__ float msq[256];
    __shared__ float lossAcc;

    const int tid = threadIdx.x;
    const int hl  = blockIdx.y;
    const int h   = h0 + hl;
    const int l0  = blockIdx.x * TL;
    const int tg  = tid & 15;    // token group: tokens t = tg + 16*jt
    const int cg  = tid >> 4;    // cluster group: clusters c = cg + 128*p + 16*jl

    if (tid == 0) lossAcc = 0.f;

    // stage x tile: xs[t*68 + k]
    const float* xbase = x + (((size_t)(b * Hh + h)) * Ll + l0) * Dd;
    for (int j = tid; j < TL * Dd / 4; j += 256) {
        int t = j >> 4, k4 = (j & 15) << 2;
        float4 v = *(const float4*)(xbase + t * Dd + k4);
        xs[t * 68 + k4 + 0] = v.x; xs[t * 68 + k4 + 1] = v.y;
        xs[t * 68 + k4 + 2] = v.z; xs[t * 68 + k4 + 3] = v.w;
    }

    float acc[4][16];
    #pragma unroll
    for (int jt = 0; jt < 4; jt++)
        #pragma unroll
        for (int jc = 0; jc < 16; jc++) acc[jt][jc] = 0.f;

    for (int p = 0; p < 2; p++) {
        __syncthreads();  // covers xs staging (p=0) / protects ms from prev-pass readers (p=1)
        const float* mbase = means + ((size_t)h * Cc + p * 128) * Dd;
        for (int j = tid; j < 128 * Dd / 4; j += 256) {
            int cr = j >> 4, k4 = (j & 15) << 2;
            float4 v = *(const float4*)(mbase + cr * Dd + k4);
            ms[cr * 68 + k4 + 0] = v.x; ms[cr * 68 + k4 + 1] = v.y;
            ms[cr * 68 + k4 + 2] = v.z; ms[cr * 68 + k4 + 3] = v.w;
        }
        __syncthreads();
        if (tid < 128) {  // |m_c|^2 for the loss
            float s = 0.f;
            #pragma unroll 8
            for (int k = 0; k < 64; k += 2) {
                float2 m = *(float2*)&ms[tid * 68 + k];
                s = fmaf(m.x, m.x, s); s = fmaf(m.y, m.y, s);
            }
            msq[p * 128 + tid] = s;
        }
        #pragma unroll 4
        for (int k = 0; k < 64; k += 2) {
            float2 xa[4];
            #pragma unroll
            for (int jt = 0; jt < 4; jt++) xa[jt] = *(float2*)&xs[(tg + 16 * jt) * 68 + k];
            float2 mb[8];
            #pragma unroll
            for (int jl = 0; jl < 8; jl++) mb[jl] = *(float2*)&ms[(cg + 16 * jl) * 68 + k];
            #pragma unroll
            for (int jt = 0; jt < 4; jt++)
                #pragma unroll
                for (int jl = 0; jl < 8; jl++) {
                    float a = acc[jt][p * 8 + jl];
                    a = fmaf(xa[jt].x, mb[jl].x, a);
                    a = fmaf(xa[jt].y, mb[jl].y, a);
                    acc[jt][p * 8 + jl] = a;
                }
        }
    }

    // dist_T writes + per-thread argmax partial (ascending c within thread -> keep-first tie rule)
    #pragma unroll
    for (int jt = 0; jt < 4; jt++) {
        int t = tg + 16 * jt;
        float bv = acc[jt][0]; int bc = cg;  // jc=0 -> c=cg
        #pragma unroll
        for (int jc = 0; jc < 16; jc++) {
            int c = cg + 128 * (jc >> 3) + 16 * (jc & 7);
            float v = acc[jt][jc];
            distT[((size_t)(hl * Cc + c)) * Ll + l0 + t] = v;
            if (jc > 0 && v > bv) { bv = v; bc = c; }
        }
        pv[t * 16 + cg] = bv; pc[t * 16 + cg] = bc;
    }
    __syncthreads();

    if (tid < TL) {
        int t = tid;
        float ss = 0.f;
        #pragma unroll 8
        for (int k = 0; k < 64; k += 2) {
            float2 v = *(float2*)&xs[t * 68 + k];
            ss = fmaf(v.x, v.x, ss); ss = fmaf(v.y, v.y, ss);
        }
        float bv = pv[t * 16]; int bc = pc[t * 16];
        #pragma unroll
        for (int g = 1; g < 16; g++) {
            float v = pv[t * 16 + g]; int c2 = pc[t * 16 + g];
            if (v > bv || (v == bv && c2 < bc)) { bv = v; bc = c2; }
        }
        buckets[((size_t)(b * Hh + h)) * Ll + l0 + t] = bc;
        atomicAdd(&lossAcc, ss - 2.f * bv + msq[bc]);
    }
    __syncthreads();
    if (tid == 0) lossP[(b * Hh + h) * (Ll / TL) + blockIdx.x] = lossAcc;
}

// ---------------- k2: exact top-32 per (h,c) column via 4-pass radix select ----------------
__device__ __forceinline__ unsigned int f2key(float f) {
    unsigned int u = __float_as_uint(f);
    return (u & 0x80000000u) ? ~u : (u | 0x80000000u);
}

__global__ __launch_bounds__(256) void k2_topk(const float* __restrict__ distT,
                                               float* __restrict__ outIdx,
                                               int b, int h0) {
    __shared__ unsigned int hist[256];
    __shared__ unsigned int gsum[16];
    __shared__ unsigned int sA, sPrefix, sNA, sEq;
    __shared__ int aboveList[32];
    __shared__ int eqList[64];
    __shared__ int comb[32];

    const int tid = threadIdx.x;
    const int c = blockIdx.x;
    const int hl = blockIdx.y;
    const int h = h0 + hl;
    const float* col = distT + ((size_t)(hl * Cc + c)) * Ll;

    unsigned int key[32];
    #pragma unroll
    for (int j = 0; j < 8; j++) {
        float4 v = *(const float4*)(col + j * 1024 + tid * 4);
        key[j * 4 + 0] = f2key(v.x); key[j * 4 + 1] = f2key(v.y);
        key[j * 4 + 2] = f2key(v.z); key[j * 4 + 3] = f2key(v.w);
    }
    if (tid == 0) { sA = 0; sPrefix = 0; }
    __syncthreads();

    for (int pass = 0; pass < 4; pass++) {
        const int shift = 24 - 8 * pass;
        unsigned int A = sA, pref = sPrefix;
        unsigned int maskHi = (pass == 0) ? 0u : (0xFFFFFFFFu << (shift + 8));
        hist[tid] = 0;
        __syncthreads();
        #pragma unroll
        for (int j = 0; j < 32; j++)
            if (((key[j] ^ pref) & maskHi) == 0)
                atomicAdd(&hist[(key[j] >> shift) & 255], 1u);
        __syncthreads();
        if (tid < 16) {
            unsigned int s = 0;
            for (int j = 0; j < 16; j++) s += hist[tid * 16 + j];
            gsum[tid] = s;
        }
        __syncthreads();
        // suffixIncl(tid)
        unsigned int suf = 0;
        int g = tid >> 4;
        for (int j = tid; j < (g + 1) * 16; j++) suf += hist[j];
        for (int j = g + 1; j < 16; j++) suf += gsum[j];
        unsigned int sufNext = suf - hist[tid];
        bool cond = (A + suf) >= Ww;
        bool condNext = (A + sufNext) >= Ww;
        if (cond && (tid == 255 || !condNext)) {
            sA = A + sufNext;
            sPrefix = pref | ((unsigned int)tid << shift);
        }
        __syncthreads();
    }

    const unsigned int T = sPrefix;
    const int nAexp = (int)sA;
    const int r = Ww - nAexp;
    if (tid == 0) { sNA = 0; sEq = 0; }
    __syncthreads();
    #pragma unroll
    for (int j = 0; j < 32; j++) {
        unsigned int kk = key[j];
        int idx = 4 * (j / 4) * 256 + tid * 4 + (j & 3);  // = (j>>2)*1024 + tid*4 + (j&3)
        if (kk > T) {
            int p2 = (int)atomicAdd(&sNA, 1u);
            if (p2 < 32) aboveList[p2] = idx;
        } else if (kk == T) {
            int p2 = (int)atomicAdd(&sEq, 1u);
            if (p2 < 64) eqList[p2] = idx;
        }
    }
    __syncthreads();
    const int nA = (int)sNA;
    const int eq = (int)sEq;
    if (eq <= 64) {
        if (tid < eq) {
            int v = eqList[tid];
            int rank = 0;
            for (int j = 0; j < eq; j++) rank += (eqList[j] < v);
            if (rank < r) comb[nA + rank] = v;
        }
    } else if (tid == 0) {  // pathological tie flood: serial, correct
        int taken = 0;
        for (int i = 0; i < Ll && taken < r; i++)
            if (f2key(col[i]) == T) comb[nA + taken++] = i;
    }
    if (tid < nA) comb[tid] = aboveList[tid];
    __syncthreads();
    if (tid < Ww) {
        int v = comb[tid];
        int rank = 0;
        #pragma unroll
        for (int j = 0; j < Ww; j++) rank += (comb[j] < v);
        outIdx[(((size_t)b * Hh + h) * Cc + c) * Ww + rank] = (float)v;
    }
}

// ---------------- k3a: per-chunk scatter-add into LDS, plain-write partials ----------------
// grid: (Bb*Hh*Ll)/rpb blocks, 256 threads. Each block owns rpb consecutive token rows
// (rpb divides Ll, so a block never crosses an (b,h) boundary).
__global__ __launch_bounds__(256) void k3a_scatter(const float* __restrict__ x,
                                                   const int* __restrict__ buckets,
                                                   float* __restrict__ partialS,
                                                   int* __restrict__ partialC,
                                                   int rpb) {
    __shared__ float sums[Cc * Dd];   // 64 KB
    __shared__ int cnt[Cc];
    const int tid = threadIdx.x;
    const int w = tid >> 6;          // token slot within quad
    const int d = tid & 63;          // dim
    const size_t row0 = (size_t)blockIdx.x * rpb;

    for (int j = tid; j < Cc * Dd; j += 256) sums[j] = 0.f;
    cnt[tid & 255] = 0;
    __syncthreads();

    const int iters = rpb >> 2;      // 4 tokens per iteration (one per wave)
    #pragma unroll 8
    for (int it = 0; it < iters; it++) {
        size_t r = row0 + (size_t)it * 4 + w;
        int bk = buckets[r];
        float v = x[r * Dd + d];
        atomicAdd(&sums[bk * Dd + d], v);
        if (d == 0) atomicAdd(&cnt[bk], 1);
    }
    __syncthreads();

    float* oS = partialS + (size_t)blockIdx.x * (Cc * Dd);
    for (int j = tid; j < Cc * Dd; j += 256) oS[j] = sums[j];
    partialC[blockIdx.x * Cc + tid] = cnt[tid];
}

// ---------------- k3b: reduce partials per (h,c), normalize, empty-cluster fallback ----------------
// grid: Hh*Cc blocks, 64 threads (one wave). Q = Ll/rpb chunks per (b,h).
__global__ __launch_bounds__(64) void k3b_finish(const float* __restrict__ partialS,
                                                 const int* __restrict__ partialC,
                                                 const float* __restrict__ means,
                                                 float* __restrict__ outMeans,
                                                 int Q) {
    const int hc = blockIdx.x;
    const int h = hc >> 8, c = hc & 255;
    const int d = threadIdx.x;

    float s = 0.f;
    for (int b2 = 0; b2 < Bb; b2++)
        for (int k = 0; k < Q; k++) {
            int pb = (b2 * Hh + h) * Q + k;
            s += partialS[(size_t)pb * (Cc * Dd) + c * Dd + d];
        }
    int cn = 0;
    for (int i = d; i < Bb * Q; i += 64) {
        int b2 = i / Q, k = i % Q;
        int pb = (b2 * Hh + h) * Q + k;
        cn += partialC[pb * Cc + c];
    }
    #pragma unroll
    for (int off = 32; off; off >>= 1) cn += __shfl_xor(cn, off);
    float t = s * s;
    #pragma unroll
    for (int off = 32; off; off >>= 1) t += __shfl_xor(t, off);
    float nrm = sqrtf(t);

    float outv = (cn == 0) ? means[((size_t)h * Cc + c) * Dd + d]
                           : s / fmaxf(nrm, 1e-12f);
    outMeans[((size_t)h * Cc + c) * Dd + d] = outv;
}

// ---------------- k4: loss reduction ----------------
__global__ __launch_bounds__(256) void k4_loss(const float* __restrict__ lossP,
                                               float* __restrict__ out) {
    __shared__ float red[256];
    const int tid = threadIdx.x;
    float s = 0.f;
    for (int i = tid; i < Bb * Hh * (Ll / TL); i += 256) s += lossP[i];
    red[tid] = s;
    __syncthreads();
    for (int off = 128; off; off >>= 1) {
        if (tid < off) red[tid] += red[tid + off];
        __syncthreads();
    }
    if (tid == 0)
        out[(size_t)Bb * Hh * Cc * Ww] = red[0] * (1e-4f / (float)((size_t)Bb * Hh * Ll * Dd));
}

extern "C" void kernel_launch(void* const* d_in, const int* in_sizes, int n_in,
                              void* d_out, int out_size, void* d_ws, size_t ws_size,
                              hipStream_t stream) {
    const float* x = (const float*)d_in[0];
    const float* means = (const float*)d_in[1];
    float* out = (float*)d_out;

    char* ws = (char*)d_ws;
    float* lossP = (float*)ws;                       // 4096 floats (16 KB)
    int* buckets = (int*)(ws + 16384);               // 262144 ints (1 MB)
    const size_t base = 16384 + 1048576;
    const size_t perH = (size_t)Cc * Ll * 4;         // 8 MB per (h) dist plane

    // choose rows-per-block for k3a so everything fits alongside >=1 dist plane
    int rpb = 512;
    size_t NB;
    while (true) {
        NB = (size_t)(Bb * Hh * Ll) / rpb;
        size_t need = base + NB * Cc * 4 + NB * (size_t)(Cc * Dd) * 4 + perH;
        if (need <= ws_size || rpb >= 4096) break;
        rpb <<= 1;
    }
    NB = (size_t)(Bb * Hh * Ll) / rpb;
    int* partialC = (int*)(ws + base);
    float* partialS = (float*)(ws + base + NB * Cc * 4);
    const size_t fixed = base + NB * Cc * 4 + NB * (size_t)(Cc * Dd) * 4;
    float* distT = (float*)(ws + fixed);

    int hStep = 8;
    while (hStep > 1 && fixed + (size_t)hStep * perH > ws_size) hStep >>= 1;

    const int IDXN = Bb * Hh * Cc * Ww;  // 262144
    for (int b = 0; b < Bb; b++) {
        for (int h0 = 0; h0 < Hh; h0 += hStep) {
            k1_gemm<<<dim3(Ll / TL, hStep), 256, 0, stream>>>(x, means, distT, buckets, lossP, b, h0);
            k2_topk<<<dim3(Cc, hStep), 256, 0, stream>>>(distT, out, b, h0);
        }
    }
    k3a_scatter<<<(int)NB, 256, 0, stream>>>(x, buckets, partialS, partialC, rpb);
    k3b_finish<<<Hh * Cc, 64, 0, stream>>>(partialS, partialC, means, out + IDXN + 1, Ll / rpb);
    k4_loss<<<1, 256, 0, stream>>>(lossP, out);
}

// Round 3
// 498.855 us; speedup vs baseline: 2.9566x; 1.1699x over previous
//
#include <hip/hip_runtime.h>
#include <hip/hip_bf16.h>

#define Bb 4
#define Hh 8
#define Ll 8192
#define Dd 64
#define Cc 256
#define Ww 32
#define TL 128   // tokens per k1 block

// ---------------- k1: dists GEMM + argmax buckets + loss partials + dist_T write ----------------
// grid (Ll/TL, hStep, bStep), block 256. thread tile: 8 tokens x 8 clusters, float4 LDS reads.
__global__ __launch_bounds__(256) void k1_gemm(const float* __restrict__ x,
                                               const float* __restrict__ means,
                                               float* __restrict__ distT,
                                               int* __restrict__ buckets,
                                               float* __restrict__ lossP,
                                               int b0, int h0) {
    __shared__ __align__(16) float ms[128 * 68];   // half of means[h] (34 KB)
    __shared__ __align__(16) float xs[TL * 68];    // token tile (34 KB)
    __shared__ float pv[TL * 4];
    __shared__ int   pc[TL * 4];
    __shared__ float msq[256];
    __shared__ float lossAcc;

    const int tid = threadIdx.x;
    const int hl  = blockIdx.y, bz = blockIdx.z;
    const int h   = h0 + hl,    b  = b0 + bz;
    const int l0  = blockIdx.x * TL;
    const int tg  = tid & 15;    // tokens t = tg + 16*jt, jt<8
    const int cg  = tid >> 4;    // clusters c = cg + 16*jl + 128*p, jl<8

    if (tid == 0) lossAcc = 0.f;

    const float* xbase = x + (((size_t)(b * Hh + h)) * Ll + l0) * Dd;
    for (int j = tid; j < TL * 16; j += 256) {
        int t = j >> 4, k4 = (j & 15) << 2;
        *(float4*)&xs[t * 68 + k4] = *(const float4*)(xbase + t * Dd + k4);
    }

    float bvr[8]; int bcr[8];
    #pragma unroll
    for (int jt = 0; jt < 8; jt++) { bvr[jt] = -3.4e38f; bcr[jt] = 0; }

    const size_t pbase = ((size_t)(bz * gridDim.y + hl)) * Cc;

    for (int p = 0; p < 2; p++) {
        __syncthreads();  // covers xs staging (p=0) / protects ms from prev-pass readers (p=1)
        const float* mbase = means + ((size_t)h * Cc + p * 128) * Dd;
        for (int j = tid; j < 128 * 16; j += 256) {
            int r = j >> 4, k4 = (j & 15) << 2;
            *(float4*)&ms[r * 68 + k4] = *(const float4*)(mbase + r * Dd + k4);
        }
        __syncthreads();
        if (tid < 128) {  // |m_c|^2 for the loss
            float s = 0.f;
            #pragma unroll
            for (int k = 0; k < 64; k += 4) {
                float4 m = *(const float4*)&ms[tid * 68 + k];
                s = fmaf(m.x, m.x, s); s = fmaf(m.y, m.y, s);
                s = fmaf(m.z, m.z, s); s = fmaf(m.w, m.w, s);
            }
            msq[(p << 7) + tid] = s;
        }

        float acc[8][8];
        #pragma unroll
        for (int jt = 0; jt < 8; jt++)
            #pragma unroll
            for (int jl = 0; jl < 8; jl++) acc[jt][jl] = 0.f;

        #pragma unroll 4
        for (int k = 0; k < 64; k += 4) {
            float4 xa[8];
            #pragma unroll
            for (int jt = 0; jt < 8; jt++) xa[jt] = *(const float4*)&xs[(tg + 16 * jt) * 68 + k];
            #pragma unroll
            for (int jl = 0; jl < 8; jl++) {
                float4 m = *(const float4*)&ms[(cg + 16 * jl) * 68 + k];
                #pragma unroll
                for (int jt = 0; jt < 8; jt++) {
                    float a = acc[jt][jl];
                    a = fmaf(xa[jt].x, m.x, a); a = fmaf(xa[jt].y, m.y, a);
                    a = fmaf(xa[jt].z, m.z, a); a = fmaf(xa[jt].w, m.w, a);
                    acc[jt][jl] = a;
                }
            }
        }

        // dist_T writes + running per-thread argmax (c strictly ascending across jl and p)
        #pragma unroll
        for (int jt = 0; jt < 8; jt++) {
            int t = tg + 16 * jt;
            #pragma unroll
            for (int jl = 0; jl < 8; jl++) {
                int cl = cg + 16 * jl + (p << 7);
                float v = acc[jt][jl];
                distT[(pbase + cl) * Ll + l0 + t] = v;
                if (v > bvr[jt]) { bvr[jt] = v; bcr[jt] = cl; }
            }
        }
    }

    // merge argmax: in-wave across the 4 cluster-groups of this wave, then LDS across waves
    #pragma unroll
    for (int jt = 0; jt < 8; jt++) {
        float bv = bvr[jt]; int bc = bcr[jt];
        #pragma unroll
        for (int off = 16; off <= 32; off <<= 1) {
            float ov = __shfl_xor(bv, off);
            int   oc = __shfl_xor(bc, off);
            if (ov > bv || (ov == bv && oc < bc)) { bv = ov; bc = oc; }
        }
        if ((tid & 48) == 0) { int t = tg + 16 * jt; pv[t * 4 + (tid >> 6)] = bv; pc[t * 4 + (tid >> 6)] = bc; }
    }
    __syncthreads();

    if (tid < TL) {
        int t = tid;
        float bv = pv[t * 4]; int bc = pc[t * 4];
        #pragma unroll
        for (int g = 1; g < 4; g++) {
            float v = pv[t * 4 + g]; int c2 = pc[t * 4 + g];
            if (v > bv || (v == bv && c2 < bc)) { bv = v; bc = c2; }
        }
        float ss = 0.f;
        #pragma unroll
        for (int k = 0; k < 64; k += 4) {
            float4 u = *(const float4*)&xs[t * 68 + k];
            ss = fmaf(u.x, u.x, ss); ss = fmaf(u.y, u.y, ss);
            ss = fmaf(u.z, u.z, ss); ss = fmaf(u.w, u.w, ss);
        }
        buckets[((size_t)(b * Hh + h)) * Ll + l0 + t] = bc;
        atomicAdd(&lossAcc, ss - 2.f * bv + msq[bc]);
    }
    __syncthreads();
    if (tid == 0) lossP[(b * Hh + h) * (Ll / TL) + blockIdx.x] = lossAcc;
}

// ---------------- k2: exact top-32 per (h,c) column via 3-pass (11/11/10-bit) radix select ----------------
__device__ __forceinline__ unsigned int f2key(float f) {
    unsigned int u = __float_as_uint(f);
    return (u & 0x80000000u) ? ~u : (u | 0x80000000u);
}

__global__ __launch_bounds__(256) void k2_topk(const float* __restrict__ distT,
                                               float* __restrict__ outIdx,
                                               int b0, int h0) {
    __shared__ unsigned int hist[2048];
    __shared__ unsigned int tsum[256];
    __shared__ unsigned int gsum[16];
    __shared__ unsigned int sA, sPrefix, sNA, sEq;
    __shared__ int aboveList[32];
    __shared__ int eqList[64];
    __shared__ int comb[32];

    const int tid = threadIdx.x;
    const int c = blockIdx.x, hl = blockIdx.y, bz = blockIdx.z;
    const int h = h0 + hl, b = b0 + bz;
    const float* col = distT + ((size_t)((bz * gridDim.y + hl) * Cc + c)) * Ll;

    unsigned int key[32];
    #pragma unroll
    for (int j = 0; j < 8; j++) {
        float4 v = *(const float4*)(col + j * 1024 + tid * 4);
        key[j * 4 + 0] = f2key(v.x); key[j * 4 + 1] = f2key(v.y);
        key[j * 4 + 2] = f2key(v.z); key[j * 4 + 3] = f2key(v.w);
    }
    if (tid == 0) { sA = 0; sPrefix = 0; }

    #pragma unroll
    for (int pass = 0; pass < 3; pass++) {
        const int shift = (pass == 0) ? 21 : (pass == 1) ? 10 : 0;
        const int width = (pass == 2) ? 10 : 11;
        const int bins = 1 << width;
        const unsigned maskHi = (pass == 0) ? 0u : (0xFFFFFFFFu << (shift + width));
        for (int j = tid; j < bins; j += 256) hist[j] = 0;
        __syncthreads();
        const unsigned A = sA, pref = sPrefix;
        #pragma unroll
        for (int j = 0; j < 32; j++)
            if (((key[j] ^ pref) & maskHi) == 0)
                atomicAdd(&hist[(key[j] >> shift) & (bins - 1)], 1u);
        __syncthreads();
        const int bpt = bins >> 8;       // bins per thread: 8,8,4
        unsigned s = 0;
        for (int q = 0; q < bpt; q++) s += hist[tid * bpt + q];
        tsum[tid] = s;
        __syncthreads();
        if (tid < 16) { unsigned g2 = 0; for (int q = 0; q < 16; q++) g2 += tsum[tid * 16 + q]; gsum[tid] = g2; }
        __syncthreads();
        unsigned St = 0;
        {   int g = tid >> 4;
            for (int t2 = tid + 1; t2 < (g + 1) * 16; t2++) St += tsum[t2];
            for (int g2 = g + 1; g2 < 16; g2++) St += gsum[g2]; }
        unsigned sufAfter = St;          // suffix-exclusive of this thread's top bin
        for (int q = bpt - 1; q >= 0; q--) {
            int D = tid * bpt + q;
            unsigned hd = hist[D];
            unsigned sufIncl = sufAfter + hd;
            bool cond = (A + sufIncl) >= Ww;
            bool condNext = (A + sufAfter) >= Ww;
            if (cond && !condNext) { sA = A + sufAfter; sPrefix = pref | ((unsigned)D << shift); }
            sufAfter = sufIncl;
        }
        __syncthreads();
    }

    const unsigned T = sPrefix;
    const int r = Ww - (int)sA;
    if (tid == 0) { sNA = 0; sEq = 0; }
    __syncthreads();
    #pragma unroll
    for (int j = 0; j < 32; j++) {
        unsigned kk = key[j];
        int idx = (j >> 2) * 1024 + tid * 4 + (j & 3);
        if (kk > T) {
            int p2 = (int)atomicAdd(&sNA, 1u);
            if (p2 < 32) aboveList[p2] = idx;
        } else if (kk == T) {
            int p2 = (int)atomicAdd(&sEq, 1u);
            if (p2 < 64) eqList[p2] = idx;
        }
    }
    __syncthreads();
    const int nA = (int)sNA;
    const int eq = (int)sEq;
    if (eq <= 64) {
        if (tid < eq) {
            int v = eqList[tid];
            int rank = 0;
            for (int j = 0; j < eq; j++) rank += (eqList[j] < v);
            if (rank < r) comb[nA + rank] = v;
        }
    } else if (tid == 0) {  // pathological tie flood: serial, correct
        int taken = 0;
        for (int i = 0; i < Ll && taken < r; i++)
            if (f2key(col[i]) == T) comb[nA + taken++] = i;
    }
    if (tid < nA) comb[tid] = aboveList[tid];
    __syncthreads();
    if (tid < Ww) {
        int v = comb[tid];
        int rank = 0;
        #pragma unroll
        for (int j = 0; j < Ww; j++) rank += (comb[j] < v);
        outIdx[(((size_t)(b * Hh + h)) * Cc + c) * Ww + rank] = (float)v;
    }
}

// ---------------- k3: counting sort by (h,cluster), then gather ----------------
__global__ __launch_bounds__(256) void k3_hist(const int* __restrict__ buckets,
                                               unsigned int* __restrict__ hist) {
    __shared__ unsigned int lh[256];
    const int tid = threadIdx.x;
    lh[tid] = 0;
    __syncthreads();
    int i = blockIdx.x * 256 + tid;
    int bk = buckets[i];
    atomicAdd(&lh[bk], 1u);
    __syncthreads();
    int h = (i >> 13) & 7;   // block spans 256 tokens of one (b,h)
    if (lh[tid]) atomicAdd(&hist[h * 256 + tid], lh[tid]);
}

__global__ __launch_bounds__(256) void k3_scan(const unsigned int* __restrict__ hist,
                                               unsigned int* __restrict__ offs,
                                               unsigned int* __restrict__ cursor) {
    __shared__ unsigned int ps[256];
    const int tid = threadIdx.x;
    unsigned int loc[8];
    unsigned s = 0;
    #pragma unroll
    for (int k = 0; k < 8; k++) { loc[k] = hist[tid * 8 + k]; s += loc[k]; }
    ps[tid] = s;
    __syncthreads();
    for (int off = 1; off < 256; off <<= 1) {
        unsigned v = (tid >= off) ? ps[tid - off] : 0;
        __syncthreads();
        ps[tid] += v;
        __syncthreads();
    }
    unsigned base = ps[tid] - s;  // exclusive
    #pragma unroll
    for (int k = 0; k < 8; k++) {
        offs[tid * 8 + k] = base;
        cursor[tid * 8 + k] = base;
        base += loc[k];
    }
    if (tid == 255) offs[2048] = ps[255];
}

__global__ __launch_bounds__(256) void k3_scatter(const int* __restrict__ buckets,
                                                  unsigned int* __restrict__ cursor,
                                                  unsigned int* __restrict__ sortedTok) {
    int i = blockIdx.x * 256 + threadIdx.x;
    int bk = buckets[i];
    int h = (i >> 13) & 7, b = i >> 16, l = i & 8191;
    unsigned pos = atomicAdd(&cursor[h * 256 + bk], 1u);
    sortedTok[pos] = (unsigned)((b << 13) | l);
}

__global__ __launch_bounds__(256) void k3_gather(const float* __restrict__ x,
                                                 const float* __restrict__ means,
                                                 const unsigned int* __restrict__ offs,
                                                 const unsigned int* __restrict__ sortedTok,
                                                 float* __restrict__ outMeans) {
    __shared__ float part[4][64];
    const int tid = threadIdx.x;
    const int w = tid >> 6, d = tid & 63;
    const int bin = blockIdx.x;
    const int h = bin >> 8, cc = bin & 255;
    const unsigned s0 = offs[bin], s1 = offs[bin + 1];
    const int n = (int)(s1 - s0);
    float acc = 0.f;
    for (int j = w; j < n; j += 4) {
        unsigned e = sortedTok[s0 + j];
        int b = e >> 13, l = e & 8191;
        acc += x[(((size_t)(b * Hh + h)) * Ll + l) * Dd + d];
    }
    part[w][d] = acc;
    __syncthreads();
    if (tid < 64) {
        float s = part[0][d] + part[1][d] + part[2][d] + part[3][d];
        float t = s * s;
        #pragma unroll
        for (int off = 32; off; off >>= 1) t += __shfl_xor(t, off);
        float nrm = sqrtf(t);
        float outv = (n == 0) ? means[((size_t)(h * Cc + cc)) * Dd + d]
                              : s / fmaxf(nrm, 1e-12f);
        outMeans[((size_t)(h * Cc + cc)) * Dd + d] = outv;
    }
}

// ---------------- k4: loss reduction ----------------
__global__ __launch_bounds__(256) void k4_loss(const float* __restrict__ lossP,
                                               float* __restrict__ out) {
    __shared__ float red[256];
    const int tid = threadIdx.x;
    float s = 0.f;
    for (int i = tid; i < Bb * Hh * (Ll / TL); i += 256) s += lossP[i];
    red[tid] = s;
    __syncthreads();
    for (int off = 128; off; off >>= 1) {
        if (tid < off) red[tid] += red[tid + off];
        __syncthreads();
    }
    if (tid == 0)
        out[(size_t)Bb * Hh * Cc * Ww] = red[0] * (1e-4f / (float)((size_t)Bb * Hh * Ll * Dd));
}

extern "C" void kernel_launch(void* const* d_in, const int* in_sizes, int n_in,
                              void* d_out, int out_size, void* d_ws, size_t ws_size,
                              hipStream_t stream) {
    (void)in_sizes; (void)n_in; (void)out_size;
    const float* x = (const float*)d_in[0];
    const float* means = (const float*)d_in[1];
    float* out = (float*)d_out;

    char* ws = (char*)d_ws;
    float* lossP = (float*)ws;                              // 2048 floats (8 KB)
    int* buckets = (int*)(ws + 8192);                       // 1 MB
    unsigned int* hist = (unsigned int*)(ws + 8192 + 1048576);       // 2048
    unsigned int* offs = hist + 2048;                       // 2049
    unsigned int* cursor = offs + 2049;                     // 2048
    unsigned int* sortedTok = cursor + 2048;                // 262144 (1 MB)
    size_t base = 8192 + 1048576 + 4ull * (2048 + 2049 + 2048) + 4ull * 262144;
    base = (base + 255) & ~255ull;
    float* distT = (float*)(ws + base);
    const size_t perPlane = (size_t)Cc * Ll * 4;            // 8 MB per (b,h) plane

    int bStep = 4, hStep = 8;
    if (base + (size_t)bStep * hStep * perPlane > ws_size) bStep = 1;
    while (hStep > 1 && base + (size_t)bStep * hStep * perPlane > ws_size) hStep >>= 1;

    hipMemsetAsync(hist, 0, 2048 * 4, stream);

    const int IDXN = Bb * Hh * Cc * Ww;  // 262144
    for (int b0 = 0; b0 < Bb; b0 += bStep) {
        for (int h0 = 0; h0 < Hh; h0 += hStep) {
            k1_gemm<<<dim3(Ll / TL, hStep, bStep), 256, 0, stream>>>(x, means, distT, buckets, lossP, b0, h0);
            k2_topk<<<dim3(Cc, hStep, bStep), 256, 0, stream>>>(distT, out, b0, h0);
        }
    }
    k3_hist<<<1024, 256, 0, stream>>>(buckets, hist);
    k3_scan<<<1, 256, 0, stream>>>(hist, offs, cursor);
    k3_scatter<<<1024, 256, 0, stream>>>(buckets, cursor, sortedTok);
    k3_gather<<<Hh * Cc, 256, 0, stream>>>(x, means, offs, sortedTok, out + IDXN + 1);
    k4_loss<<<1, 256, 0, stream>>>(lossP, out);
}